// Round 10
// baseline (58.428 us; speedup 1.0000x reference)
//
#include <hip/hip_runtime.h>

#define S 512
#define B 128
#define H 1024

// ---------------------------------------------------------------------------
// calc_u_one: u = hidden @ W in ONE kernel (R9-proven). Grid 256 = 16 bg x
// 16 ht; block computes 8 b x 64 h over full K via in-block 16-way k-split.
// hidden staged in LDS (coalesced), bank-skewed k-walk, 16-way LDS reduce.
// ---------------------------------------------------------------------------
__global__ __launch_bounds__(256) void calc_u_one(const float* __restrict__ hidden,
                                                  const float* __restrict__ W,
                                                  float* __restrict__ u) {
    const int t  = threadIdx.x;
    const int th = t & 15;            // h-quad: 4 h each -> 64 h per block
    const int kg = t >> 4;            // 0..15, owns 64 k
    const int bg = blockIdx.x & 15;   // 8-b group
    const int ht = blockIdx.x >> 4;   // 64-h stripe
    const int b0 = bg * 8;
    const int h0 = ht * 64 + th * 4;

    __shared__ float hs[8][1028];     // staged hidden rows (+4 pad: bank skew)
    __shared__ float red[16][8][64];  // kg-partials for the reduce

    const float4* __restrict__ hv = reinterpret_cast<const float4*>(hidden + (size_t)b0 * H);
#pragma unroll
    for (int i = 0; i < 8; ++i) {
        const float4 v = hv[i * 256 + t];
        *reinterpret_cast<float4*>(&hs[i][t * 4]) = v;
    }
    __syncthreads();

    float4 acc[8];
#pragma unroll
    for (int j = 0; j < 8; ++j) acc[j] = make_float4(0.f, 0.f, 0.f, 0.f);

#pragma unroll 4
    for (int kk = 0; kk < 64; ++kk) {
        const int k = kg * 64 + ((kk + kg * 8) & 63);   // bank-skewed walk
        const float4 w = *reinterpret_cast<const float4*>(W + (size_t)k * H + h0);
#pragma unroll
        for (int j = 0; j < 8; ++j) {
            const float hb = hs[j][k];                  // LDS broadcast
            acc[j].x = fmaf(hb, w.x, acc[j].x);
            acc[j].y = fmaf(hb, w.y, acc[j].y);
            acc[j].z = fmaf(hb, w.z, acc[j].z);
            acc[j].w = fmaf(hb, w.w, acc[j].w);
        }
    }

    __syncthreads();
#pragma unroll
    for (int j = 0; j < 8; ++j)
        *reinterpret_cast<float4*>(&red[kg][j][th * 4]) = acc[j];
    __syncthreads();

    if (t < 128) {
        const int b  = t >> 4;
        const int hq = (t & 15) * 4;
        float4 s = *reinterpret_cast<const float4*>(&red[0][b][hq]);
#pragma unroll
        for (int g = 1; g < 16; ++g) {
            const float4 v = *reinterpret_cast<const float4*>(&red[g][b][hq]);
            s.x += v.x; s.y += v.y; s.z += v.z; s.w += v.w;
        }
        *reinterpret_cast<float4*>(u + (size_t)(b0 + b) * H + ht * 64 + hq) = s;
    }
}

// ---------------------------------------------------------------------------
// calc_scores (contiguous-stream variant): scores[b][s] = dot(enc[s][b], u[b]).
// Block = (b-quad q, s-octet so): stages u[b0..b0+3] into 16 KB LDS once
// (8 blocks/CU -> 128 KB LDS/CU, occupancy preserved). Wave wid handles
// s = so*8 + wid*2 + {0,1}; per s the jb-loop walks b0..b0+3 -> each wave
// reads two CONTIGUOUS 16 KB runs (vs R9's eight scattered 4 KB rows with
// 512 KB hops). Same 268 MB total; mechanism under test: DRAM row/bank
// locality of long sequential runs. u via ds_read_b128, lane-consecutive
// 16 B = conflict-free. No fences/atomics (R2/R7 measured losers).
// ---------------------------------------------------------------------------
__global__ __launch_bounds__(256) void calc_scores(const float* __restrict__ enc,
                                                   const float* __restrict__ u,
                                                   float* __restrict__ scores) {
    const int t    = threadIdx.x;
    const int wid  = t >> 6;
    const int lane = t & 63;
    const int q  = blockIdx.x & 31;    // b-quad: b0 = q*4
    const int so = blockIdx.x >> 5;    // s-octet: 0..63
    const int b0 = q * 4;

    __shared__ float us[4 * 1024];     // u[b0..b0+3][:] = 16 KB

    // stage u: 4096 contiguous floats = 1024 float4, coalesced
    const float4* __restrict__ uv = reinterpret_cast<const float4*>(u + (size_t)b0 * H);
#pragma unroll
    for (int i = 0; i < 4; ++i) {
        const float4 v = uv[i * 256 + t];
        *reinterpret_cast<float4*>(&us[(i * 256 + t) * 4]) = v;
    }
    __syncthreads();

    float acc[2][4];
#pragma unroll
    for (int js = 0; js < 2; ++js) {
        const int s = so * 8 + wid * 2 + js;
#pragma unroll
        for (int jb = 0; jb < 4; ++jb) {
            const float4* __restrict__ e4 =
                reinterpret_cast<const float4*>(enc + ((size_t)s * B + (b0 + jb)) * H);
            const float4* __restrict__ u4 =
                reinterpret_cast<const float4*>(&us[jb * 1024]);
            const float4 e0 = e4[lane];
            const float4 e1 = e4[64 + lane];
            const float4 e2 = e4[128 + lane];
            const float4 e3 = e4[192 + lane];
            const float4 u0 = u4[lane];
            const float4 u1 = u4[64 + lane];
            const float4 u2 = u4[128 + lane];
            const float4 u3 = u4[192 + lane];
            float a = e0.x * u0.x + e0.y * u0.y + e0.z * u0.z + e0.w * u0.w;
            a = fmaf(e1.x, u1.x, a); a = fmaf(e1.y, u1.y, a);
            a = fmaf(e1.z, u1.z, a); a = fmaf(e1.w, u1.w, a);
            a = fmaf(e2.x, u2.x, a); a = fmaf(e2.y, u2.y, a);
            a = fmaf(e2.z, u2.z, a); a = fmaf(e2.w, u2.w, a);
            a = fmaf(e3.x, u3.x, a); a = fmaf(e3.y, u3.y, a);
            a = fmaf(e3.z, u3.z, a); a = fmaf(e3.w, u3.w, a);
            acc[js][jb] = a;
        }
    }

#pragma unroll
    for (int js = 0; js < 2; ++js)
#pragma unroll
        for (int jb = 0; jb < 4; ++jb)
#pragma unroll
            for (int off = 32; off >= 1; off >>= 1)
                acc[js][jb] += __shfl_xor(acc[js][jb], off, 64);

    if (lane == 0) {
#pragma unroll
        for (int js = 0; js < 2; ++js) {
            const int s = so * 8 + wid * 2 + js;
#pragma unroll
            for (int jb = 0; jb < 4; ++jb)
                scores[(size_t)(b0 + jb) * S + s] = acc[js][jb];
        }
    }
}

// ---------------------------------------------------------------------------
// softmax over s per b. b_attn never computed: constant per row -> cancels.
// ---------------------------------------------------------------------------
__global__ __launch_bounds__(256) void softmax_rows(const float* __restrict__ scores,
                                                    float* __restrict__ out) {
    const int b = blockIdx.x;
    const int t = threadIdx.x;
    const int wid = t >> 6, lane = t & 63;
    const float* __restrict__ row = scores + (size_t)b * S;
    float v0 = row[t];
    float v1 = row[t + 256];

    __shared__ float sm[4], ss[4];

    float m = fmaxf(v0, v1);
#pragma unroll
    for (int off = 32; off >= 1; off >>= 1)
        m = fmaxf(m, __shfl_xor(m, off, 64));
    if (lane == 0) sm[wid] = m;
    __syncthreads();
    m = fmaxf(fmaxf(sm[0], sm[1]), fmaxf(sm[2], sm[3]));

    float e0 = __expf(v0 - m);
    float e1 = __expf(v1 - m);
    float sum = e0 + e1;
#pragma unroll
    for (int off = 32; off >= 1; off >>= 1)
        sum += __shfl_xor(sum, off, 64);
    if (lane == 0) ss[wid] = sum;
    __syncthreads();
    sum = ss[0] + ss[1] + ss[2] + ss[3];

    const float inv = 1.f / sum;
    out[(size_t)b * S + t]       = e0 * inv;
    out[(size_t)b * S + t + 256] = e1 * inv;
}

extern "C" void kernel_launch(void* const* d_in, const int* in_sizes, int n_in,
                              void* d_out, int out_size, void* d_ws, size_t ws_size,
                              hipStream_t stream) {
    const float* hidden = (const float*)d_in[0];   // [1,B,H]
    const float* enc    = (const float*)d_in[1];   // [S,B,H]
    const float* W      = (const float*)d_in[2];   // [H,H]
    // d_in[3] = b_attn: unused — constant per row, cancels in softmax.

    float* u      = (float*)d_ws;        // B*H floats
    float* scores = u + (size_t)B * H;   // B*S floats
    float* out    = (float*)d_out;       // [B,1,S]

    calc_u_one  <<<256,  256, 0, stream>>>(hidden, W, u);
    calc_scores <<<2048, 256, 0, stream>>>(enc, u, scores);
    softmax_rows<<<128,  256, 0, stream>>>(scores, out);
}

// Round 11
// 57.430 us; speedup vs baseline: 1.0174x; 1.0174x over previous
//
#include <hip/hip_runtime.h>

#define S 512
#define B 128
#define H 1024

// ---------------------------------------------------------------------------
// calc_u_one: u = hidden @ W in ONE kernel (R9-proven). Grid 256 = 16 bg x
// 16 ht; block computes 8 b x 64 h over full K via in-block 16-way k-split.
// hidden staged in LDS (coalesced), bank-skewed k-walk, 16-way LDS reduce.
// ---------------------------------------------------------------------------
__global__ __launch_bounds__(256) void calc_u_one(const float* __restrict__ hidden,
                                                  const float* __restrict__ W,
                                                  float* __restrict__ u) {
    const int t  = threadIdx.x;
    const int th = t & 15;            // h-quad: 4 h each -> 64 h per block
    const int kg = t >> 4;            // 0..15, owns 64 k
    const int bg = blockIdx.x & 15;   // 8-b group
    const int ht = blockIdx.x >> 4;   // 64-h stripe
    const int b0 = bg * 8;
    const int h0 = ht * 64 + th * 4;

    __shared__ float hs[8][1028];     // staged hidden rows (+4 pad: bank skew)
    __shared__ float red[16][8][64];  // kg-partials for the reduce

    const float4* __restrict__ hv = reinterpret_cast<const float4*>(hidden + (size_t)b0 * H);
#pragma unroll
    for (int i = 0; i < 8; ++i) {
        const float4 v = hv[i * 256 + t];
        *reinterpret_cast<float4*>(&hs[i][t * 4]) = v;
    }
    __syncthreads();

    float4 acc[8];
#pragma unroll
    for (int j = 0; j < 8; ++j) acc[j] = make_float4(0.f, 0.f, 0.f, 0.f);

#pragma unroll 4
    for (int kk = 0; kk < 64; ++kk) {
        const int k = kg * 64 + ((kk + kg * 8) & 63);   // bank-skewed walk
        const float4 w = *reinterpret_cast<const float4*>(W + (size_t)k * H + h0);
#pragma unroll
        for (int j = 0; j < 8; ++j) {
            const float hb = hs[j][k];                  // LDS broadcast
            acc[j].x = fmaf(hb, w.x, acc[j].x);
            acc[j].y = fmaf(hb, w.y, acc[j].y);
            acc[j].z = fmaf(hb, w.z, acc[j].z);
            acc[j].w = fmaf(hb, w.w, acc[j].w);
        }
    }

    __syncthreads();
#pragma unroll
    for (int j = 0; j < 8; ++j)
        *reinterpret_cast<float4*>(&red[kg][j][th * 4]) = acc[j];
    __syncthreads();

    if (t < 128) {
        const int b  = t >> 4;
        const int hq = (t & 15) * 4;
        float4 s = *reinterpret_cast<const float4*>(&red[0][b][hq]);
#pragma unroll
        for (int g = 1; g < 16; ++g) {
            const float4 v = *reinterpret_cast<const float4*>(&red[g][b][hq]);
            s.x += v.x; s.y += v.y; s.z += v.z; s.w += v.w;
        }
        *reinterpret_cast<float4*>(u + (size_t)(b0 + b) * H + ht * 64 + hq) = s;
    }
}

// ---------------------------------------------------------------------------
// calc_scores (dense-front variant): scores[b][s] = dot(enc[s][b], u[b]).
// Identical to the R9-proven kernel EXCEPT the s-iteration order:
//   R9 : wave owned s in [sp*8, sp*8+8)  -> 8192 private 32 KB walks; the
//        instantaneous device access set is a 1/8-dense front over all
//        268 MB (DRAM row-locality killer hypothesis, ~5.3 TB/s observed).
//   Now: s = i*64 + sp -> at inner step i, ALL waves read s in
//        [i*64, i*64+64) x all b = one dense 32 MB window advancing
//        sequentially, like a fill/copy front (fills measure 7.0 TB/s).
// Per-wave per-step: same 4 KB contiguous row via 4x dwordx4; u in 16
// VGPRs; shuffle-reduce tail unchanged. Bijective s-cover, deterministic.
// ---------------------------------------------------------------------------
__global__ __launch_bounds__(256) void calc_scores(const float* __restrict__ enc,
                                                   const float* __restrict__ u,
                                                   float* __restrict__ scores) {
    const int wid  = threadIdx.x >> 6;
    const int lane = threadIdx.x & 63;
    const int w  = blockIdx.x * 4 + wid;   // 0..8191
    const int b  = w & (B - 1);
    const int sp = w >> 7;                 // 0..63

    const float4* __restrict__ u4 = reinterpret_cast<const float4*>(u + (size_t)b * H);
    const float4 uu0 = u4[lane];
    const float4 uu1 = u4[64 + lane];
    const float4 uu2 = u4[128 + lane];
    const float4 uu3 = u4[192 + lane];

    float acc[8];
#pragma unroll
    for (int i = 0; i < 8; ++i) {
        const int s = i * 64 + sp;         // dense device-wide front at step i
        const float4* __restrict__ e4 =
            reinterpret_cast<const float4*>(enc + ((size_t)s * B + b) * H);
        const float4 e0 = e4[lane];
        const float4 e1 = e4[64 + lane];
        const float4 e2 = e4[128 + lane];
        const float4 e3 = e4[192 + lane];
        float a = e0.x * uu0.x + e0.y * uu0.y + e0.z * uu0.z + e0.w * uu0.w;
        a = fmaf(e1.x, uu1.x, a); a = fmaf(e1.y, uu1.y, a);
        a = fmaf(e1.z, uu1.z, a); a = fmaf(e1.w, uu1.w, a);
        a = fmaf(e2.x, uu2.x, a); a = fmaf(e2.y, uu2.y, a);
        a = fmaf(e2.z, uu2.z, a); a = fmaf(e2.w, uu2.w, a);
        a = fmaf(e3.x, uu3.x, a); a = fmaf(e3.y, uu3.y, a);
        a = fmaf(e3.z, uu3.z, a); a = fmaf(e3.w, uu3.w, a);
        acc[i] = a;
    }
#pragma unroll
    for (int i = 0; i < 8; ++i)
#pragma unroll
        for (int off = 32; off >= 1; off >>= 1)
            acc[i] += __shfl_xor(acc[i], off, 64);

    if (lane == 0) {
#pragma unroll
        for (int i = 0; i < 8; ++i)
            scores[(size_t)b * S + i * 64 + sp] = acc[i];
    }
}

// ---------------------------------------------------------------------------
// softmax over s per b. b_attn never computed: constant per row -> cancels.
// ---------------------------------------------------------------------------
__global__ __launch_bounds__(256) void softmax_rows(const float* __restrict__ scores,
                                                    float* __restrict__ out) {
    const int b = blockIdx.x;
    const int t = threadIdx.x;
    const int wid = t >> 6, lane = t & 63;
    const float* __restrict__ row = scores + (size_t)b * S;
    float v0 = row[t];
    float v1 = row[t + 256];

    __shared__ float sm[4], ss[4];

    float m = fmaxf(v0, v1);
#pragma unroll
    for (int off = 32; off >= 1; off >>= 1)
        m = fmaxf(m, __shfl_xor(m, off, 64));
    if (lane == 0) sm[wid] = m;
    __syncthreads();
    m = fmaxf(fmaxf(sm[0], sm[1]), fmaxf(sm[2], sm[3]));

    float e0 = __expf(v0 - m);
    float e1 = __expf(v1 - m);
    float sum = e0 + e1;
#pragma unroll
    for (int off = 32; off >= 1; off >>= 1)
        sum += __shfl_xor(sum, off, 64);
    if (lane == 0) ss[wid] = sum;
    __syncthreads();
    sum = ss[0] + ss[1] + ss[2] + ss[3];

    const float inv = 1.f / sum;
    out[(size_t)b * S + t]       = e0 * inv;
    out[(size_t)b * S + t + 256] = e1 * inv;
}

extern "C" void kernel_launch(void* const* d_in, const int* in_sizes, int n_in,
                              void* d_out, int out_size, void* d_ws, size_t ws_size,
                              hipStream_t stream) {
    const float* hidden = (const float*)d_in[0];   // [1,B,H]
    const float* enc    = (const float*)d_in[1];   // [S,B,H]
    const float* W      = (const float*)d_in[2];   // [H,H]
    // d_in[3] = b_attn: unused — constant per row, cancels in softmax.

    float* u      = (float*)d_ws;        // B*H floats
    float* scores = u + (size_t)B * H;   // B*S floats
    float* out    = (float*)d_out;       // [B,1,S]

    calc_u_one  <<<256,  256, 0, stream>>>(hidden, W, u);
    calc_scores <<<2048, 256, 0, stream>>>(enc, u, scores);
    softmax_rows<<<128,  256, 0, stream>>>(scores, out);
}